// Round 17
// baseline (845.341 us; speedup 1.0000x reference)
//
#include <hip/hip_runtime.h>

typedef __bf16 bf16_t;
typedef __bf16 bf16x8 __attribute__((ext_vector_type(8)));
typedef float  f32x4  __attribute__((ext_vector_type(4)));

#define S_IMG 4096
#define S_TXT 512
#define S_TOT 4608
#define DMODEL 3072
#define NH 24
#define HD 128

__device__ __forceinline__ void load_lds16(const void* g, void* l) {
  __builtin_amdgcn_global_load_lds(
      (const __attribute__((address_space(1))) void*)g,
      (__attribute__((address_space(3))) void*)l, 16, 0, 0);
}

#define BARRIER() do { asm volatile("" ::: "memory");                          \
                       __builtin_amdgcn_s_barrier();                           \
                       asm volatile("" ::: "memory"); } while (0)

// ---------------- fp32 -> bf16 convert (single + fused pair) ---------------
__global__ __launch_bounds__(256) void f2b_kernel(const float* __restrict__ in,
                                                  bf16_t* __restrict__ out, int n) {
  int i = (blockIdx.x * 256 + threadIdx.x) * 4;
  if (i >= n) return;
  float4 v = *(const float4*)(in + i);
  union { bf16_t b[4]; uint2 u; } pk;
  pk.b[0] = (bf16_t)v.x; pk.b[1] = (bf16_t)v.y;
  pk.b[2] = (bf16_t)v.z; pk.b[3] = (bf16_t)v.w;
  *(uint2*)(out + i) = pk.u;
}

__global__ __launch_bounds__(256) void f2b2_kernel(
    const float* __restrict__ in0, bf16_t* __restrict__ out0,
    const float* __restrict__ in1, bf16_t* __restrict__ out1, int nb) {
  int b = blockIdx.x;
  const float* in = (b < nb) ? in0 : in1;
  bf16_t* out = (b < nb) ? out0 : out1;
  int i = (((b < nb) ? b : b - nb) * 256 + threadIdx.x) * 4;
  float4 v = *(const float4*)(in + i);
  union { bf16_t b[4]; uint2 u; } pk;
  pk.b[0] = (bf16_t)v.x; pk.b[1] = (bf16_t)v.y;
  pk.b[2] = (bf16_t)v.z; pk.b[3] = (bf16_t)v.w;
  *(uint2*)(out + i) = pk.u;
}

// ---------------- dual NT GEMM: 1024-thr / 16-wave, 256x256 tile -----------
// B may be a stack of nmat matrices (bx spans nbt = nmat*12 col-tiles);
// output matrix m goes to C + m*matStride.
template <typename OT>
__global__ __launch_bounds__(1024) void gemm1024(
    const bf16_t* __restrict__ A0, const bf16_t* __restrict__ B0,
    OT* __restrict__ C0, const float* __restrict__ bias0, int mt0,
    const bf16_t* __restrict__ A1, const bf16_t* __restrict__ B1,
    OT* __restrict__ C1, const float* __restrict__ bias1,
    int nbt, size_t matStride, int swzq)
{
  const int NT = DMODEL / 64;  // 48
  __shared__ bf16_t As[2][2][256 * 32];
  __shared__ bf16_t Bs[2][2][256 * 32];

  int bid = blockIdx.x;
  int t = (bid & 7) * swzq + (bid >> 3);
  int nb0 = mt0 * nbt;
  const bf16_t* A; const bf16_t* B; OT* C; const float* bias;
  if (t < nb0) { A = A0; B = B0; C = C0; bias = bias0; }
  else { t -= nb0; A = A1; B = B1; C = C1; bias = bias1; }
  int bx = t % nbt, by = t / nbt;
  int mat = bx / 12;

  int tid = threadIdx.x;
  int lane = tid & 63, wid = tid >> 6;
  int l15 = lane & 15, lg = lane >> 4;
  int wm = wid >> 2, wn = wid & 3;
  int sx = (lg ^ ((l15 >> 1) & 3)) * 8;

  const bf16_t* Ag = A + (size_t)by * 256 * DMODEL;
  const bf16_t* Bg = B + (size_t)bx * 256 * DMODEL;

  int ur0 = tid >> 2;
  int uc0 = ((tid & 3) ^ ((tid >> 3) & 3)) * 8;

  auto stage = [&](int ht) {
    int T = ht >> 2, sl = ht & 3, kh = sl >> 1;
    const bf16_t* G = (sl & 1) ? Bg : Ag;
    bf16_t* L = (sl & 1) ? &Bs[T & 1][kh][0] : &As[T & 1][kh][0];
    int kbase = T * 64 + kh * 32;
    load_lds16(G + (size_t)ur0 * DMODEL + kbase + uc0,
               (char*)L + (size_t)tid * 16);
  };

  f32x4 acc[4][4];
  f32x4 zero = {0.f, 0.f, 0.f, 0.f};
  #pragma unroll
  for (int m = 0; m < 4; m++)
    #pragma unroll
    for (int n = 0; n < 4; n++) acc[m][n] = zero;

  stage(0); stage(1); stage(2); stage(3); stage(4); stage(5);
  asm volatile("s_waitcnt vmcnt(4)" ::: "memory");
  BARRIER();

  for (int T = 0; T < NT; ++T) {
    int cur = T & 1;
    bf16x8 af[4], bfr[4];

    {
      const bf16_t* A0s = &As[cur][0][0];
      const bf16_t* B0s = &Bs[cur][0][0];
      #pragma unroll
      for (int n = 0; n < 4; n++)
        bfr[n] = *(const bf16x8*)(B0s + (wn * 64 + n * 16 + l15) * 32 + sx);
      #pragma unroll
      for (int m = 0; m < 4; m++)
        af[m] = *(const bf16x8*)(A0s + (wm * 64 + m * 16 + l15) * 32 + sx);
    }
    if (T + 1 < NT) { stage(4 * T + 6); stage(4 * T + 7); }
    BARRIER();
    __builtin_amdgcn_s_setprio(1);
    #pragma unroll
    for (int m = 0; m < 4; m++)
      #pragma unroll
      for (int n = 0; n < 4; n++)
        acc[m][n] = __builtin_amdgcn_mfma_f32_16x16x32_bf16(af[m], bfr[n], acc[m][n], 0, 0, 0);
    __builtin_amdgcn_s_setprio(0);
    if (T < NT - 1) asm volatile("s_waitcnt vmcnt(4)" ::: "memory");
    else            asm volatile("s_waitcnt vmcnt(0)" ::: "memory");
    BARRIER();

    {
      const bf16_t* A1s = &As[cur][1][0];
      const bf16_t* B1s = &Bs[cur][1][0];
      #pragma unroll
      for (int n = 0; n < 4; n++)
        bfr[n] = *(const bf16x8*)(B1s + (wn * 64 + n * 16 + l15) * 32 + sx);
      #pragma unroll
      for (int m = 0; m < 4; m++)
        af[m] = *(const bf16x8*)(A1s + (wm * 64 + m * 16 + l15) * 32 + sx);
    }
    if (T + 2 < NT) { stage(4 * T + 8); stage(4 * T + 9); }
    BARRIER();
    __builtin_amdgcn_s_setprio(1);
    #pragma unroll
    for (int m = 0; m < 4; m++)
      #pragma unroll
      for (int n = 0; n < 4; n++)
        acc[m][n] = __builtin_amdgcn_mfma_f32_16x16x32_bf16(af[m], bfr[n], acc[m][n], 0, 0, 0);
    __builtin_amdgcn_s_setprio(0);
    if (T < NT - 2)       asm volatile("s_waitcnt vmcnt(4)" ::: "memory");
    else if (T == NT - 2) asm volatile("s_waitcnt vmcnt(2)" ::: "memory");
    BARRIER();
  }

  OT* Cm = C + (size_t)mat * matStride;
  size_t row0 = (size_t)by * 256 + wm * 64;
  int col0 = (bx % 12) * 256 + wn * 64;
  #pragma unroll
  for (int n = 0; n < 4; n++) {
    int col = col0 + n * 16 + l15;
    float bv = bias ? bias[col] : 0.f;
    #pragma unroll
    for (int m = 0; m < 4; m++) {
      #pragma unroll
      for (int r = 0; r < 4; r++) {
        size_t row = row0 + m * 16 + lg * 4 + r;
        Cm[row * DMODEL + col] = (OT)(acc[m][n][r] + bv);
      }
    }
  }
}

// ---------------- V GEMM with transposed epilogue: writes Vt[h][d][s] ------
__global__ __launch_bounds__(1024) void gemm1024V(
    const bf16_t* __restrict__ A0, const bf16_t* __restrict__ B0,
    const float* __restrict__ bias0, int mt0, int soff0,
    const bf16_t* __restrict__ A1, const bf16_t* __restrict__ B1,
    const float* __restrict__ bias1, int soff1,
    bf16_t* __restrict__ Vt, int swzq)
{
  const int NT = DMODEL / 64;  // 48
  __shared__ bf16_t As[2][2][256 * 32];
  __shared__ bf16_t Bs[2][2][256 * 32];

  int bid = blockIdx.x;
  int t = (bid & 7) * swzq + (bid >> 3);
  int nb0 = mt0 * 12;
  const bf16_t* A; const bf16_t* B; const float* bias; int soff;
  if (t < nb0) { A = A0; B = B0; bias = bias0; soff = soff0; }
  else { t -= nb0; A = A1; B = B1; bias = bias1; soff = soff1; }
  int bx = t % 12, by = t / 12;

  int tid = threadIdx.x;
  int lane = tid & 63, wid = tid >> 6;
  int l15 = lane & 15, lg = lane >> 4;
  int wm = wid >> 2, wn = wid & 3;
  int sx = (lg ^ ((l15 >> 1) & 3)) * 8;

  const bf16_t* Ag = A + (size_t)by * 256 * DMODEL;
  const bf16_t* Bg = B + (size_t)bx * 256 * DMODEL;

  int ur0 = tid >> 2;
  int uc0 = ((tid & 3) ^ ((tid >> 3) & 3)) * 8;

  auto stage = [&](int ht) {
    int T = ht >> 2, sl = ht & 3, kh = sl >> 1;
    const bf16_t* G = (sl & 1) ? Bg : Ag;
    bf16_t* L = (sl & 1) ? &Bs[T & 1][kh][0] : &As[T & 1][kh][0];
    int kbase = T * 64 + kh * 32;
    load_lds16(G + (size_t)ur0 * DMODEL + kbase + uc0,
               (char*)L + (size_t)tid * 16);
  };

  f32x4 acc[4][4];
  f32x4 zero = {0.f, 0.f, 0.f, 0.f};
  #pragma unroll
  for (int m = 0; m < 4; m++)
    #pragma unroll
    for (int n = 0; n < 4; n++) acc[m][n] = zero;

  stage(0); stage(1); stage(2); stage(3); stage(4); stage(5);
  asm volatile("s_waitcnt vmcnt(4)" ::: "memory");
  BARRIER();

  for (int T = 0; T < NT; ++T) {
    int cur = T & 1;
    bf16x8 af[4], bfr[4];

    {
      const bf16_t* A0s = &As[cur][0][0];
      const bf16_t* B0s = &Bs[cur][0][0];
      #pragma unroll
      for (int n = 0; n < 4; n++)
        bfr[n] = *(const bf16x8*)(B0s + (wn * 64 + n * 16 + l15) * 32 + sx);
      #pragma unroll
      for (int m = 0; m < 4; m++)
        af[m] = *(const bf16x8*)(A0s + (wm * 64 + m * 16 + l15) * 32 + sx);
    }
    if (T + 1 < NT) { stage(4 * T + 6); stage(4 * T + 7); }
    BARRIER();
    __builtin_amdgcn_s_setprio(1);
    #pragma unroll
    for (int m = 0; m < 4; m++)
      #pragma unroll
      for (int n = 0; n < 4; n++)
        acc[m][n] = __builtin_amdgcn_mfma_f32_16x16x32_bf16(af[m], bfr[n], acc[m][n], 0, 0, 0);
    __builtin_amdgcn_s_setprio(0);
    if (T < NT - 1) asm volatile("s_waitcnt vmcnt(4)" ::: "memory");
    else            asm volatile("s_waitcnt vmcnt(0)" ::: "memory");
    BARRIER();

    {
      const bf16_t* A1s = &As[cur][1][0];
      const bf16_t* B1s = &Bs[cur][1][0];
      #pragma unroll
      for (int n = 0; n < 4; n++)
        bfr[n] = *(const bf16x8*)(B1s + (wn * 64 + n * 16 + l15) * 32 + sx);
      #pragma unroll
      for (int m = 0; m < 4; m++)
        af[m] = *(const bf16x8*)(A1s + (wm * 64 + m * 16 + l15) * 32 + sx);
    }
    if (T + 2 < NT) { stage(4 * T + 8); stage(4 * T + 9); }
    BARRIER();
    __builtin_amdgcn_s_setprio(1);
    #pragma unroll
    for (int m = 0; m < 4; m++)
      #pragma unroll
      for (int n = 0; n < 4; n++)
        acc[m][n] = __builtin_amdgcn_mfma_f32_16x16x32_bf16(af[m], bfr[n], acc[m][n], 0, 0, 0);
    __builtin_amdgcn_s_setprio(0);
    if (T < NT - 2)       asm volatile("s_waitcnt vmcnt(4)" ::: "memory");
    else if (T == NT - 2) asm volatile("s_waitcnt vmcnt(2)" ::: "memory");
    BARRIER();
  }

  // ---- transposed epilogue ----
  BARRIER();
  bf16_t* slab = (wid < 8) ? &As[0][0][0] + (size_t)wid * 4096
                           : &Bs[0][0][0] + (size_t)(wid - 8) * 4096;
  int col0 = bx * 256 + wn * 64;
  #pragma unroll
  for (int n = 0; n < 4; n++) {
    int col = n * 16 + l15;
    float bv = bias ? bias[col0 + col] : 0.f;
    int msk = (col & 7) << 3;
    #pragma unroll
    for (int m = 0; m < 4; m++) {
      int rowl = m * 16 + lg * 4;
      union { bf16_t b[4]; unsigned long long ll; } pk;
      #pragma unroll
      for (int r = 0; r < 4; r++) pk.b[r] = (bf16_t)(acc[m][n][r] + bv);
      *(unsigned long long*)&slab[col * 64 + (rowl ^ msk)] = pk.ll;
    }
  }
  asm volatile("s_waitcnt lgkmcnt(0)" ::: "memory");
  __builtin_amdgcn_sched_barrier(0);
  int hh = col0 / HD;
  int dbase = col0 % HD;
  size_t sbase = (size_t)soff + (size_t)by * 256 + wm * 64;
  #pragma unroll
  for (int it = 0; it < 8; it++) {
    int d = it * 8 + (lane >> 3);
    int s8 = (lane & 7) * 8;
    int msk = (d & 7) << 3;
    bf16x8 v = *(const bf16x8*)&slab[d * 64 + (s8 ^ msk)];
    *(bf16x8*)(Vt + (size_t)(hh * HD + dbase + d) * S_TOT + sbase + s8) = v;
  }
}

// ---------------- RMSNorm + RoPE (+txt bias, +fold scale*log2e into Q) -----
__global__ __launch_bounds__(256) void qk_post(
    const bf16_t* __restrict__ qbuf, const bf16_t* __restrict__ kbuf,
    const float* __restrict__ cosb, const float* __restrict__ sinb,
    const float* __restrict__ wqn, const float* __restrict__ wkn,
    const float* __restrict__ waqn, const float* __restrict__ wakn,
    const float* __restrict__ baq, const float* __restrict__ bak,
    bf16_t* __restrict__ Qh, bf16_t* __restrict__ Kh)
{
  int gw = blockIdx.x * 4 + (threadIdx.x >> 6);
  int lane = threadIdx.x & 63;
  int s = gw / NH, h = gw - (gw / NH) * NH;
  if (s >= S_TOT) return;
  int d0 = lane * 2;
  const bf16_t* qp = qbuf + (size_t)s * DMODEL + h * HD + d0;
  const bf16_t* kp = kbuf + (size_t)s * DMODEL + h * HD + d0;
  float q0 = (float)qp[0], q1 = (float)qp[1];
  float k0 = (float)kp[0], k1 = (float)kp[1];
  if (s < S_TXT) {                       // text-stream linear has bias
    q0 += baq[h * HD + d0]; q1 += baq[h * HD + d0 + 1];
    k0 += bak[h * HD + d0]; k1 += bak[h * HD + d0 + 1];
  }
  float sq = q0 * q0 + q1 * q1, sk = k0 * k0 + k1 * k1;
  #pragma unroll
  for (int m = 1; m < 64; m <<= 1) { sq += __shfl_xor(sq, m); sk += __shfl_xor(sk, m); }
  float rq = rsqrtf(sq * (1.f / HD) + 1e-5f);
  float rk = rsqrtf(sk * (1.f / HD) + 1e-5f);
  const float* qn = (s < S_TXT) ? waqn : wqn;
  const float* kn = (s < S_TXT) ? wakn : wkn;
  q0 *= rq * qn[d0]; q1 *= rq * qn[d0 + 1];
  k0 *= rk * kn[d0]; k1 *= rk * kn[d0 + 1];
  float c0 = cosb[s * HD + d0], c1 = cosb[s * HD + d0 + 1];
  float s0 = sinb[s * HD + d0], s1 = sinb[s * HD + d0 + 1];
  const float SCALE = 0.1275174319942397f;  // 1/sqrt(128) * log2(e)
  float oq0 = (q0 * c0 - q1 * s0) * SCALE;
  float oq1 = (q1 * c1 + q0 * s1) * SCALE;
  float ok0 = k0 * c0 - k1 * s0;
  float ok1 = k1 * c1 + k0 * s1;
  size_t ob = ((size_t)h * S_TOT + s) * HD + d0;
  union { bf16_t b[2]; unsigned int u; } pq, pk;
  pq.b[0] = (bf16_t)oq0; pq.b[1] = (bf16_t)oq1;
  pk.b[0] = (bf16_t)ok0; pk.b[1] = (bf16_t)ok1;
  *(unsigned int*)(Qh + ob) = pq.u;
  *(unsigned int*)(Kh + ob) = pk.u;
}

// ---------------- flash attention: round-7 engine (KVBLK=64, unroll-2) -----
__global__ __launch_bounds__(256, 2) void attn_kernel(
    const bf16_t* __restrict__ Qh, const bf16_t* __restrict__ Kh,
    const bf16_t* __restrict__ Vt, bf16_t* __restrict__ O)
{
  int bid = blockIdx.x;
  int orig = (bid & 7) * 108 + (bid >> 3);
  int h = orig / 36;
  int q0 = (orig % 36) * 128;

  int tid = threadIdx.x, w = tid >> 6, lane = tid & 63;
  int l15 = lane & 15, lg = lane >> 4;
  int sw = (l15 & 7) << 4;

  __shared__ bf16_t Ks[2][64 * 128];
  __shared__ bf16_t Vs[2][128 * 64];
  __shared__ bf16_t Ps[4][32 * 64];

  const bf16_t* Kbase = Kh + (size_t)h * S_TOT * HD;
  const bf16_t* Vbase = Vt + (size_t)h * HD * S_TOT;
  bf16_t* Pw = &Ps[w][0];

  bf16x8 qf[2][4];
  #pragma unroll
  for (int qh = 0; qh < 2; qh++) {
    const bf16_t* Qrow = Qh + ((size_t)h * S_TOT + q0 + w * 32 + qh * 16 + l15) * HD + lg * 8;
    #pragma unroll
    for (int dc = 0; dc < 4; dc++) qf[qh][dc] = *(const bf16x8*)(Qrow + dc * 32);
  }

  f32x4 o[2][8];
  f32x4 zero = {0.f, 0.f, 0.f, 0.f};
  #pragma unroll
  for (int qh = 0; qh < 2; qh++)
    #pragma unroll
    for (int i = 0; i < 8; i++) o[qh][i] = zero;
  float m0 = -1e30f, m1 = -1e30f, l0 = 0.f, l1 = 0.f;

#define STAGE(buf, kt) do {                                                    \
    _Pragma("unroll")                                                          \
    for (int i_ = 0; i_ < 4; i_++) {                                           \
      int Lb = (tid + i_ * 256) * 16; int row = Lb >> 8, cb = Lb & 255;        \
      int sb = cb ^ ((row & 7) << 4);                                          \
      load_lds16(Kbase + (size_t)((kt) + row) * HD + (sb >> 1),                \
                 (char*)Ks[buf] + Lb);                                         \
    }                                                                          \
    _Pragma("unroll")                                                          \
    for (int i_ = 0; i_ < 4; i_++) {                                           \
      int Lb = (tid + i_ * 256) * 16; int row = Lb >> 7, cb = Lb & 127;        \
      int sb = cb ^ ((row & 7) << 4);                                          \
      load_lds16(Vbase + (size_t)row * S_TOT + (kt) + (sb >> 1),               \
                 (char*)Vs[buf] + Lb);                                         \
    }                                                                          \
  } while (0)

#define BODY(CUR) do {                                                         \
    f32x4 sacc[2][4];                                                          \
    _Pragma("unroll")                                                          \
    for (int qh = 0; qh < 2; qh++)                                             \
      _Pragma("unroll")                                                        \
      for (int c = 0; c < 4; c++) sacc[qh][c] = zero;                          \
    const char* Kc = (const char*)Ks[CUR];                                     \
    _Pragma("unroll")                                                          \
    for (int c = 0; c < 4; c++) {                                              \
      int row = c * 16 + l15;                                                  \
      int rs = (row & 7) << 4;                                                 \
      const char* kr = Kc + row * 256;                                         \
      _Pragma("unroll")                                                        \
      for (int dc = 0; dc < 4; dc++) {                                         \
        bf16x8 kf = *(const bf16x8*)(kr + ((dc * 64 + lg * 16) ^ rs));         \
        sacc[0][c] = __builtin_amdgcn_mfma_f32_16x16x32_bf16(kf, qf[0][dc], sacc[0][c], 0, 0, 0); \
        sacc[1][c] = __builtin_amdgcn_mfma_f32_16x16x32_bf16(kf, qf[1][dc], sacc[1][c], 0, 0, 0); \
      }                                                                        \
    }                                                                          \
    float px0 = sacc[0][0][0], px1 = sacc[1][0][0];                            \
    _Pragma("unroll")                                                          \
    for (int c = 0; c < 4; c++)                                                \
      _Pragma("unroll")                                                        \
      for (int r = 0; r < 4; r++) {                                            \
        px0 = fmaxf(px0, sacc[0][c][r]);                                       \
        px1 = fmaxf(px1, sacc[1][c][r]);                                       \
      }                                                                        \
    px0 = fmaxf(px0, __shfl_xor(px0, 16)); px0 = fmaxf(px0, __shfl_xor(px0, 32)); \
    px1 = fmaxf(px1, __shfl_xor(px1, 16)); px1 = fmaxf(px1, __shfl_xor(px1, 32)); \
    bool need = (px0 > m0 + 8.f) || (px1 > m1 + 8.f);                          \
    if (__any(need)) {                                                         \
      float mn0 = fmaxf(m0, px0), mn1 = fmaxf(m1, px1);                        \
      float a0 = exp2f(m0 - mn0), a1 = exp2f(m1 - mn1);                        \
      m0 = mn0; m1 = mn1; l0 *= a0; l1 *= a1;                                  \
      _Pragma("unroll")                                                        \
      for (int r = 0; r < 4; r++) {                                            \
        float f0 = __shfl(a0, lg * 4 + r);                                     \
        float f1 = __shfl(a1, lg * 4 + r);                                     \
        _Pragma("unroll")                                                      \
        for (int dn = 0; dn < 8; dn++) { o[0][dn][r] *= f0; o[1][dn][r] *= f1; } \
      }                                                                        \
    }                                                                          \
    _Pragma("unroll")                                                          \
    for (int qh = 0; qh < 2; qh++) {                                           \
      float m = qh ? m1 : m0;                                                  \
      float rsum = 0.f;                                                        \
      char* Prow = (char*)Pw + (qh * 16 + l15) * 128;                          \
      _Pragma("unroll")                                                        \
      for (int c = 0; c < 4; c++) {                                            \
        union { bf16_t b[4]; uint2 u; } pk;                                    \
        _Pragma("unroll")                                                      \
        for (int r = 0; r < 4; r++) {                                          \
          float p = exp2f(sacc[qh][c][r] - m);                                 \
          rsum += p;                                                           \
          pk.b[r] = (bf16_t)p;                                                 \
        }                                                                      \
        *(uint2*)(Prow + ((c * 32 + lg * 8) ^ sw)) = pk.u;                     \
      }                                                                        \
      rsum += __shfl_xor(rsum, 16);                                            \
      rsum += __shfl_xor(rsum, 32);                                            \
      if (qh) l1 += rsum; else l0 += rsum;                                     \
    }                                                                          \
    bf16x8 pf[2][2];                                                           \
    _Pragma("unroll")                                                          \
    for (int qh = 0; qh < 2; qh++) {                                           \
      const char* Prow = (const char*)Pw + (qh * 16 + l15) * 128;              \
      _Pragma("unroll")                                                        \
      for (int kc = 0; kc < 2; kc++)                                           \
        pf[qh][kc] = *(const bf16x8*)(Prow + ((kc * 64 + lg * 16) ^ sw));      \
    }                                                                          \
    const char* Vc = (const char*)Vs[CUR];                                     \
    _Pragma("unroll")                                                          \
    for (int dn = 0; dn < 8; dn++) {                                           \
      int row = dn * 16 + l15;                                                 \
      int rs2 = (row & 7) << 4;                                                \
      const char* vr = Vc + row * 128;                                         \
      bf16x8 vf0 = *(const bf16x8*)(vr + ((lg * 16) ^ rs2));                   \
      bf16x8 vf1 = *(const bf16x8*)(vr + ((64 + lg * 16) ^ rs2));              \
      o[0][dn] = __builtin_amdgcn_mfma_f32_16x16x32_bf16(pf[0][0], vf0, o[0][dn], 0, 0, 0); \
      o[0][dn] = __builtin_amdgcn_mfma_f32_16x16x32_bf16(pf[0][1], vf1, o[0][dn], 0, 0, 0); \
      o[1][dn] = __builtin_amdgcn_mfma_f32_16x16x32_bf16(pf[1][0], vf0, o[1][dn], 0, 0, 0); \
      o[1][dn] = __builtin_amdgcn_mfma_f32_16x16x32_bf16(pf[1][1], vf1, o[1][dn], 0, 0, 0); \
    }                                                                          \
  } while (0)

  STAGE(0, 0);
  __syncthreads();

  const int NT = S_TOT / 64;  // 72 (even)
  for (int tt = 0; tt < NT; tt += 2) {
    STAGE(1, (tt + 1) * 64);
    BODY(0);
    __syncthreads();
    if (tt + 2 < NT) STAGE(0, (tt + 2) * 64);
    BODY(1);
    __syncthreads();
  }
#undef BODY
#undef STAGE

  #pragma unroll
  for (int qh = 0; qh < 2; qh++) {
    #pragma unroll
    for (int r = 0; r < 4; r++) {
      float lv = __shfl(qh ? l1 : l0, lg * 4 + r);
      float inv = 1.f / lv;
      size_t srow = (size_t)q0 + w * 32 + qh * 16 + lg * 4 + r;
      #pragma unroll
      for (int dn = 0; dn < 8; dn++)
        O[srow * DMODEL + h * HD + dn * 16 + l15] = (bf16_t)(o[qh][dn][r] * inv);
    }
  }
}

// ---------------------------------------------------------------------------
extern "C" void kernel_launch(void* const* d_in, const int* in_sizes, int n_in,
                              void* d_out, int out_size, void* d_ws, size_t ws_size,
                              hipStream_t stream) {
  const float* hidden = (const float*)d_in[0];
  const float* enc    = (const float*)d_in[1];
  const float* ropec  = (const float*)d_in[2];
  const float* ropes  = (const float*)d_in[3];
  const float* Wq  = (const float*)d_in[4];
  const float* Wk  = (const float*)d_in[5];
  const float* Wv  = (const float*)d_in[6];
  const float* Waq = (const float*)d_in[7];
  const float* baq = (const float*)d_in[8];
  const float* Wak = (const float*)d_in[9];
  const float* bak = (const float*)d_in[10];
  const float* Wav = (const float*)d_in[11];
  const float* bav = (const float*)d_in[12];
  const float* Wo  = (const float*)d_in[13];
  const float* bo  = (const float*)d_in[14];
  const float* Wao = (const float*)d_in[15];
  const float* bao = (const float*)d_in[16];
  const float* wqn = (const float*)d_in[17];
  const float* wkn = (const float*)d_in[18];
  const float* waqn = (const float*)d_in[19];
  const float* wakn = (const float*)d_in[20];

  const size_t WSZ = (size_t)DMODEL * DMODEL;     // 9,437,184
  const size_t SEQSZ = (size_t)S_TOT * DMODEL;    // 14,155,776 (= 1.5*WSZ)
  if (ws_size < (2 * WSZ + 6 * SEQSZ) * sizeof(bf16_t)) return;

  bf16_t* s0   = (bf16_t*)d_ws;
  bf16_t* s1   = s0 + WSZ;
  bf16_t* xbi  = s1 + WSZ;
  bf16_t* xbt  = xbi + (size_t)S_IMG * DMODEL;
  bf16_t* qbuf = xbi + SEQSZ;
  bf16_t* kbuf = qbuf + SEQSZ;
  bf16_t* vbuf = kbuf + SEQSZ;   // dead (V writes Vh directly)
  bf16_t* Kh   = vbuf + SEQSZ;
  bf16_t* Vh   = Kh + SEQSZ;
  bf16_t* Qh   = xbi;      // alias: xb dead after QKV GEMMs
  bf16_t* attn_o = qbuf;   // alias: qbuf dead after qk_post
  float* outf = (float*)d_out;

  // Q+K weight stacks during the merged GEMM (dead regions):
  // img [Wq;Wk] -> Kh.. (2*WSZ; spills 0.5*WSZ into Vh, consumed before
  // gemm1024V writes Vh). txt [Waq;Wak] -> s0+s1 (2*WSZ contiguous).
  bf16_t* wqk_i = Kh;
  bf16_t* wqk_t = s0;

  f2b_kernel<<<S_IMG * DMODEL / 1024, 256, 0, stream>>>(hidden, xbi, S_IMG * DMODEL);
  f2b_kernel<<<S_TXT * DMODEL / 1024, 256, 0, stream>>>(enc, xbt, S_TXT * DMODEL);

  const int WB = (int)(WSZ / 1024);
  // merged Q+K GEMM: img 16x24 + txt 2x24 = 432 = 8*54 blocks
  f2b2_kernel<<<2 * WB, 256, 0, stream>>>(Wq, wqk_i,       Waq, wqk_t,       WB);
  f2b2_kernel<<<2 * WB, 256, 0, stream>>>(Wk, wqk_i + WSZ, Wak, wqk_t + WSZ, WB);
  gemm1024<bf16_t><<<432, 1024, 0, stream>>>(
      xbi, wqk_i, qbuf + (size_t)S_TXT * DMODEL, nullptr, 16,
      xbt, wqk_t, qbuf, nullptr, 24, SEQSZ, 54);

  // V: fused transpose epilogue writes Vh[h][d][s] directly
  f2b2_kernel<<<2 * WB, 256, 0, stream>>>(Wv, s0, Wav, s1, WB);
  gemm1024V<<<216, 1024, 0, stream>>>(
      xbi, s0, nullptr, 16, S_TXT,
      xbt, s1, bav, 0, Vh, 27);

  qk_post<<<S_TOT * NH / 4, 256, 0, stream>>>(qbuf, kbuf, ropec, ropes,
                                              wqn, wkn, waqn, wakn, baq, bak, Qh, Kh);

  attn_kernel<<<36 * 24, 256, 0, stream>>>(Qh, Kh, Vh, attn_o);

  f2b2_kernel<<<2 * WB, 256, 0, stream>>>(Wo, s0, Wao, s1, WB);
  gemm1024<float><<<216, 1024, 0, stream>>>(
      attn_o + (size_t)S_TXT * DMODEL, s0, outf, bo, 16,
      attn_o, s1, outf + (size_t)S_IMG * DMODEL, bao, 12, 0, 27);
}

// Round 18
// 837.203 us; speedup vs baseline: 1.0097x; 1.0097x over previous
//
#include <hip/hip_runtime.h>

typedef __bf16 bf16_t;
typedef __bf16 bf16x8 __attribute__((ext_vector_type(8)));
typedef float  f32x4  __attribute__((ext_vector_type(4)));

#define S_IMG 4096
#define S_TXT 512
#define S_TOT 4608
#define DMODEL 3072
#define NH 24
#define HD 128

__device__ __forceinline__ void load_lds16(const void* g, void* l) {
  __builtin_amdgcn_global_load_lds(
      (const __attribute__((address_space(1))) void*)g,
      (__attribute__((address_space(3))) void*)l, 16, 0, 0);
}

#define BARRIER() do { asm volatile("" ::: "memory");                          \
                       __builtin_amdgcn_s_barrier();                           \
                       asm volatile("" ::: "memory"); } while (0)

// ---------------- fp32 -> bf16 convert (single + fused pair) ---------------
__global__ __launch_bounds__(256) void f2b_kernel(const float* __restrict__ in,
                                                  bf16_t* __restrict__ out, int n) {
  int i = (blockIdx.x * 256 + threadIdx.x) * 4;
  if (i >= n) return;
  float4 v = *(const float4*)(in + i);
  union { bf16_t b[4]; uint2 u; } pk;
  pk.b[0] = (bf16_t)v.x; pk.b[1] = (bf16_t)v.y;
  pk.b[2] = (bf16_t)v.z; pk.b[3] = (bf16_t)v.w;
  *(uint2*)(out + i) = pk.u;
}

__global__ __launch_bounds__(256) void f2b2_kernel(
    const float* __restrict__ in0, bf16_t* __restrict__ out0,
    const float* __restrict__ in1, bf16_t* __restrict__ out1, int nb) {
  int b = blockIdx.x;
  const float* in = (b < nb) ? in0 : in1;
  bf16_t* out = (b < nb) ? out0 : out1;
  int i = (((b < nb) ? b : b - nb) * 256 + threadIdx.x) * 4;
  float4 v = *(const float4*)(in + i);
  union { bf16_t b[4]; uint2 u; } pk;
  pk.b[0] = (bf16_t)v.x; pk.b[1] = (bf16_t)v.y;
  pk.b[2] = (bf16_t)v.z; pk.b[3] = (bf16_t)v.w;
  *(uint2*)(out + i) = pk.u;
}

// ---------------- dual NT GEMM: 1024-thr / 16-wave, 256x256 tile -----------
template <typename OT>
__global__ __launch_bounds__(1024) void gemm1024(
    const bf16_t* __restrict__ A0, const bf16_t* __restrict__ B0,
    OT* __restrict__ C0, const float* __restrict__ bias0, int mt0,
    const bf16_t* __restrict__ A1, const bf16_t* __restrict__ B1,
    OT* __restrict__ C1, const float* __restrict__ bias1, int swzq)
{
  const int NT = DMODEL / 64;  // 48
  __shared__ bf16_t As[2][2][256 * 32];
  __shared__ bf16_t Bs[2][2][256 * 32];

  int bid = blockIdx.x;
  int t = (bid & 7) * swzq + (bid >> 3);
  int nb0 = mt0 * 12;
  const bf16_t* A; const bf16_t* B; OT* C; const float* bias;
  if (t < nb0) { A = A0; B = B0; C = C0; bias = bias0; }
  else { t -= nb0; A = A1; B = B1; C = C1; bias = bias1; }
  int bx = t % 12, by = t / 12;

  int tid = threadIdx.x;
  int lane = tid & 63, wid = tid >> 6;
  int l15 = lane & 15, lg = lane >> 4;
  int wm = wid >> 2, wn = wid & 3;
  int sx = (lg ^ ((l15 >> 1) & 3)) * 8;

  const bf16_t* Ag = A + (size_t)by * 256 * DMODEL;
  const bf16_t* Bg = B + (size_t)bx * 256 * DMODEL;

  int ur0 = tid >> 2;
  int uc0 = ((tid & 3) ^ ((tid >> 3) & 3)) * 8;

  auto stage = [&](int ht) {
    int T = ht >> 2, sl = ht & 3, kh = sl >> 1;
    const bf16_t* G = (sl & 1) ? Bg : Ag;
    bf16_t* L = (sl & 1) ? &Bs[T & 1][kh][0] : &As[T & 1][kh][0];
    int kbase = T * 64 + kh * 32;
    load_lds16(G + (size_t)ur0 * DMODEL + kbase + uc0,
               (char*)L + (size_t)tid * 16);
  };

  f32x4 acc[4][4];
  f32x4 zero = {0.f, 0.f, 0.f, 0.f};
  #pragma unroll
  for (int m = 0; m < 4; m++)
    #pragma unroll
    for (int n = 0; n < 4; n++) acc[m][n] = zero;

  stage(0); stage(1); stage(2); stage(3); stage(4); stage(5);
  asm volatile("s_waitcnt vmcnt(4)" ::: "memory");
  BARRIER();

  for (int T = 0; T < NT; ++T) {
    int cur = T & 1;
    bf16x8 af[4], bfr[4];

    {
      const bf16_t* A0s = &As[cur][0][0];
      const bf16_t* B0s = &Bs[cur][0][0];
      #pragma unroll
      for (int n = 0; n < 4; n++)
        bfr[n] = *(const bf16x8*)(B0s + (wn * 64 + n * 16 + l15) * 32 + sx);
      #pragma unroll
      for (int m = 0; m < 4; m++)
        af[m] = *(const bf16x8*)(A0s + (wm * 64 + m * 16 + l15) * 32 + sx);
    }
    if (T + 1 < NT) { stage(4 * T + 6); stage(4 * T + 7); }
    BARRIER();
    __builtin_amdgcn_s_setprio(1);
    #pragma unroll
    for (int m = 0; m < 4; m++)
      #pragma unroll
      for (int n = 0; n < 4; n++)
        acc[m][n] = __builtin_amdgcn_mfma_f32_16x16x32_bf16(af[m], bfr[n], acc[m][n], 0, 0, 0);
    __builtin_amdgcn_s_setprio(0);
    if (T < NT - 1) asm volatile("s_waitcnt vmcnt(4)" ::: "memory");
    else            asm volatile("s_waitcnt vmcnt(0)" ::: "memory");
    BARRIER();

    {
      const bf16_t* A1s = &As[cur][1][0];
      const bf16_t* B1s = &Bs[cur][1][0];
      #pragma unroll
      for (int n = 0; n < 4; n++)
        bfr[n] = *(const bf16x8*)(B1s + (wn * 64 + n * 16 + l15) * 32 + sx);
      #pragma unroll
      for (int m = 0; m < 4; m++)
        af[m] = *(const bf16x8*)(A1s + (wm * 64 + m * 16 + l15) * 32 + sx);
    }
    if (T + 2 < NT) { stage(4 * T + 8); stage(4 * T + 9); }
    BARRIER();
    __builtin_amdgcn_s_setprio(1);
    #pragma unroll
    for (int m = 0; m < 4; m++)
      #pragma unroll
      for (int n = 0; n < 4; n++)
        acc[m][n] = __builtin_amdgcn_mfma_f32_16x16x32_bf16(af[m], bfr[n], acc[m][n], 0, 0, 0);
    __builtin_amdgcn_s_setprio(0);
    if (T < NT - 2)       asm volatile("s_waitcnt vmcnt(4)" ::: "memory");
    else if (T == NT - 2) asm volatile("s_waitcnt vmcnt(2)" ::: "memory");
    BARRIER();
  }

  size_t row0 = (size_t)by * 256 + wm * 64;
  int col0 = bx * 256 + wn * 64;
  #pragma unroll
  for (int n = 0; n < 4; n++) {
    int col = col0 + n * 16 + l15;
    float bv = bias ? bias[col] : 0.f;
    #pragma unroll
    for (int m = 0; m < 4; m++) {
      #pragma unroll
      for (int r = 0; r < 4; r++) {
        size_t row = row0 + m * 16 + lg * 4 + r;
        C[row * DMODEL + col] = (OT)(acc[m][n][r] + bv);
      }
    }
  }
}

// ---------------- V GEMM with transposed epilogue: writes Vt[h][d][s] ------
// Same 16-wave pipeline; epilogue transposes each wave's 64x64 (s x feat)
// tile through its private 8KB LDS slab (XOR swizzle row^((col&7)<<3)),
// then stores 128B-contiguous along s. Replaces the v_trans pass.
__global__ __launch_bounds__(1024) void gemm1024V(
    const bf16_t* __restrict__ A0, const bf16_t* __restrict__ B0,
    const float* __restrict__ bias0, int mt0, int soff0,
    const bf16_t* __restrict__ A1, const bf16_t* __restrict__ B1,
    const float* __restrict__ bias1, int soff1,
    bf16_t* __restrict__ Vt, int swzq)
{
  const int NT = DMODEL / 64;  // 48
  __shared__ bf16_t As[2][2][256 * 32];
  __shared__ bf16_t Bs[2][2][256 * 32];

  int bid = blockIdx.x;
  int t = (bid & 7) * swzq + (bid >> 3);
  int nb0 = mt0 * 12;
  const bf16_t* A; const bf16_t* B; const float* bias; int soff;
  if (t < nb0) { A = A0; B = B0; bias = bias0; soff = soff0; }
  else { t -= nb0; A = A1; B = B1; bias = bias1; soff = soff1; }
  int bx = t % 12, by = t / 12;

  int tid = threadIdx.x;
  int lane = tid & 63, wid = tid >> 6;
  int l15 = lane & 15, lg = lane >> 4;
  int wm = wid >> 2, wn = wid & 3;
  int sx = (lg ^ ((l15 >> 1) & 3)) * 8;

  const bf16_t* Ag = A + (size_t)by * 256 * DMODEL;
  const bf16_t* Bg = B + (size_t)bx * 256 * DMODEL;

  int ur0 = tid >> 2;
  int uc0 = ((tid & 3) ^ ((tid >> 3) & 3)) * 8;

  auto stage = [&](int ht) {
    int T = ht >> 2, sl = ht & 3, kh = sl >> 1;
    const bf16_t* G = (sl & 1) ? Bg : Ag;
    bf16_t* L = (sl & 1) ? &Bs[T & 1][kh][0] : &As[T & 1][kh][0];
    int kbase = T * 64 + kh * 32;
    load_lds16(G + (size_t)ur0 * DMODEL + kbase + uc0,
               (char*)L + (size_t)tid * 16);
  };

  f32x4 acc[4][4];
  f32x4 zero = {0.f, 0.f, 0.f, 0.f};
  #pragma unroll
  for (int m = 0; m < 4; m++)
    #pragma unroll
    for (int n = 0; n < 4; n++) acc[m][n] = zero;

  stage(0); stage(1); stage(2); stage(3); stage(4); stage(5);
  asm volatile("s_waitcnt vmcnt(4)" ::: "memory");
  BARRIER();

  for (int T = 0; T < NT; ++T) {
    int cur = T & 1;
    bf16x8 af[4], bfr[4];

    {
      const bf16_t* A0s = &As[cur][0][0];
      const bf16_t* B0s = &Bs[cur][0][0];
      #pragma unroll
      for (int n = 0; n < 4; n++)
        bfr[n] = *(const bf16x8*)(B0s + (wn * 64 + n * 16 + l15) * 32 + sx);
      #pragma unroll
      for (int m = 0; m < 4; m++)
        af[m] = *(const bf16x8*)(A0s + (wm * 64 + m * 16 + l15) * 32 + sx);
    }
    if (T + 1 < NT) { stage(4 * T + 6); stage(4 * T + 7); }
    BARRIER();
    __builtin_amdgcn_s_setprio(1);
    #pragma unroll
    for (int m = 0; m < 4; m++)
      #pragma unroll
      for (int n = 0; n < 4; n++)
        acc[m][n] = __builtin_amdgcn_mfma_f32_16x16x32_bf16(af[m], bfr[n], acc[m][n], 0, 0, 0);
    __builtin_amdgcn_s_setprio(0);
    if (T < NT - 1) asm volatile("s_waitcnt vmcnt(4)" ::: "memory");
    else            asm volatile("s_waitcnt vmcnt(0)" ::: "memory");
    BARRIER();

    {
      const bf16_t* A1s = &As[cur][1][0];
      const bf16_t* B1s = &Bs[cur][1][0];
      #pragma unroll
      for (int n = 0; n < 4; n++)
        bfr[n] = *(const bf16x8*)(B1s + (wn * 64 + n * 16 + l15) * 32 + sx);
      #pragma unroll
      for (int m = 0; m < 4; m++)
        af[m] = *(const bf16x8*)(A1s + (wm * 64 + m * 16 + l15) * 32 + sx);
    }
    if (T + 2 < NT) { stage(4 * T + 8); stage(4 * T + 9); }
    BARRIER();
    __builtin_amdgcn_s_setprio(1);
    #pragma unroll
    for (int m = 0; m < 4; m++)
      #pragma unroll
      for (int n = 0; n < 4; n++)
        acc[m][n] = __builtin_amdgcn_mfma_f32_16x16x32_bf16(af[m], bfr[n], acc[m][n], 0, 0, 0);
    __builtin_amdgcn_s_setprio(0);
    if (T < NT - 2)       asm volatile("s_waitcnt vmcnt(4)" ::: "memory");
    else if (T == NT - 2) asm volatile("s_waitcnt vmcnt(2)" ::: "memory");
    BARRIER();
  }

  // ---- transposed epilogue ----
  BARRIER();   // all waves past K-loop; LDS reusable
  bf16_t* slab = (wid < 8) ? &As[0][0][0] + (size_t)wid * 4096
                           : &Bs[0][0][0] + (size_t)(wid - 8) * 4096;
  int col0 = bx * 256 + wn * 64;
  // store: acc(row=s, col=feat) -> slab[col*64 + (row ^ ((col&7)<<3))]
  #pragma unroll
  for (int n = 0; n < 4; n++) {
    int col = n * 16 + l15;
    float bv = bias ? bias[col0 + col] : 0.f;
    int msk = (col & 7) << 3;
    #pragma unroll
    for (int m = 0; m < 4; m++) {
      int rowl = m * 16 + lg * 4;       // 4-aligned; msk has bits>=3 -> contig 4
      union { bf16_t b[4]; unsigned long long ll; } pk;
      #pragma unroll
      for (int r = 0; r < 4; r++) pk.b[r] = (bf16_t)(acc[m][n][r] + bv);
      *(unsigned long long*)&slab[col * 64 + (rowl ^ msk)] = pk.ll;
    }
  }
  asm volatile("s_waitcnt lgkmcnt(0)" ::: "memory");   // wave-local RAW
  __builtin_amdgcn_sched_barrier(0);
  int hh = col0 / HD;
  int dbase = col0 % HD;                 // 0 or 64
  size_t sbase = (size_t)soff + (size_t)by * 256 + wm * 64;
  #pragma unroll
  for (int it = 0; it < 8; it++) {
    int d = it * 8 + (lane >> 3);
    int s8 = (lane & 7) * 8;
    int msk = (d & 7) << 3;
    bf16x8 v = *(const bf16x8*)&slab[d * 64 + (s8 ^ msk)];
    *(bf16x8*)(Vt + (size_t)(hh * HD + dbase + d) * S_TOT + sbase + s8) = v;
  }
}

// ---------------- RMSNorm + RoPE (+fold softmax scale * log2e into Q) ------
__global__ __launch_bounds__(256) void qk_post(
    const bf16_t* __restrict__ qbuf, const bf16_t* __restrict__ kbuf,
    const float* __restrict__ cosb, const float* __restrict__ sinb,
    const float* __restrict__ wqn, const float* __restrict__ wkn,
    const float* __restrict__ waqn, const float* __restrict__ wakn,
    bf16_t* __restrict__ Qh, bf16_t* __restrict__ Kh)
{
  int gw = blockIdx.x * 4 + (threadIdx.x >> 6);
  int lane = threadIdx.x & 63;
  int s = gw / NH, h = gw - (gw / NH) * NH;
  if (s >= S_TOT) return;
  int d0 = lane * 2;
  const bf16_t* qp = qbuf + (size_t)s * DMODEL + h * HD + d0;
  const bf16_t* kp = kbuf + (size_t)s * DMODEL + h * HD + d0;
  float q0 = (float)qp[0], q1 = (float)qp[1];
  float k0 = (float)kp[0], k1 = (float)kp[1];
  float sq = q0 * q0 + q1 * q1, sk = k0 * k0 + k1 * k1;
  #pragma unroll
  for (int m = 1; m < 64; m <<= 1) { sq += __shfl_xor(sq, m); sk += __shfl_xor(sk, m); }
  float rq = rsqrtf(sq * (1.f / HD) + 1e-5f);
  float rk = rsqrtf(sk * (1.f / HD) + 1e-5f);
  const float* qn = (s < S_TXT) ? waqn : wqn;
  const float* kn = (s < S_TXT) ? wakn : wkn;
  q0 *= rq * qn[d0]; q1 *= rq * qn[d0 + 1];
  k0 *= rk * kn[d0]; k1 *= rk * kn[d0 + 1];
  float c0 = cosb[s * HD + d0], c1 = cosb[s * HD + d0 + 1];
  float s0 = sinb[s * HD + d0], s1 = sinb[s * HD + d0 + 1];
  const float SCALE = 0.1275174319942397f;  // 1/sqrt(128) * log2(e)
  float oq0 = (q0 * c0 - q1 * s0) * SCALE;
  float oq1 = (q1 * c1 + q0 * s1) * SCALE;
  float ok0 = k0 * c0 - k1 * s0;
  float ok1 = k1 * c1 + k0 * s1;
  size_t ob = ((size_t)h * S_TOT + s) * HD + d0;
  union { bf16_t b[2]; unsigned int u; } pq, pk;
  pq.b[0] = (bf16_t)oq0; pq.b[1] = (bf16_t)oq1;
  pk.b[0] = (bf16_t)ok0; pk.b[1] = (bf16_t)ok1;
  *(unsigned int*)(Qh + ob) = pq.u;
  *(unsigned int*)(Kh + ob) = pk.u;
}

// ---------------- flash attention: round-7 engine (KVBLK=64, unroll-2) -----
__global__ __launch_bounds__(256, 2) void attn_kernel(
    const bf16_t* __restrict__ Qh, const bf16_t* __restrict__ Kh,
    const bf16_t* __restrict__ Vt, bf16_t* __restrict__ O)
{
  int bid = blockIdx.x;
  int orig = (bid & 7) * 108 + (bid >> 3);
  int h = orig / 36;
  int q0 = (orig % 36) * 128;

  int tid = threadIdx.x, w = tid >> 6, lane = tid & 63;
  int l15 = lane & 15, lg = lane >> 4;
  int sw = (l15 & 7) << 4;

  __shared__ bf16_t Ks[2][64 * 128];
  __shared__ bf16_t Vs[2][128 * 64];
  __shared__ bf16_t Ps[4][32 * 64];

  const bf16_t* Kbase = Kh + (size_t)h * S_TOT * HD;
  const bf16_t* Vbase = Vt + (size_t)h * HD * S_TOT;
  bf16_t* Pw = &Ps[w][0];

  bf16x8 qf[2][4];
  #pragma unroll
  for (int qh = 0; qh < 2; qh++) {
    const bf16_t* Qrow = Qh + ((size_t)h * S_TOT + q0 + w * 32 + qh * 16 + l15) * HD + lg * 8;
    #pragma unroll
    for (int dc = 0; dc < 4; dc++) qf[qh][dc] = *(const bf16x8*)(Qrow + dc * 32);
  }

  f32x4 o[2][8];
  f32x4 zero = {0.f, 0.f, 0.f, 0.f};
  #pragma unroll
  for (int qh = 0; qh < 2; qh++)
    #pragma unroll
    for (int i = 0; i < 8; i++) o[qh][i] = zero;
  float m0 = -1e30f, m1 = -1e30f, l0 = 0.f, l1 = 0.f;

#define STAGE(buf, kt) do {                                                    \
    _Pragma("unroll")                                                          \
    for (int i_ = 0; i_ < 4; i_++) {                                           \
      int Lb = (tid + i_ * 256) * 16; int row = Lb >> 8, cb = Lb & 255;        \
      int sb = cb ^ ((row & 7) << 4);                                          \
      load_lds16(Kbase + (size_t)((kt) + row) * HD + (sb >> 1),                \
                 (char*)Ks[buf] + Lb);                                         \
    }                                                                          \
    _Pragma("unroll")                                                          \
    for (int i_ = 0; i_ < 4; i_++) {                                           \
      int Lb = (tid + i_ * 256) * 16; int row = Lb >> 7, cb = Lb & 127;        \
      int sb = cb ^ ((row & 7) << 4);                                          \
      load_lds16(Vbase + (size_t)row * S_TOT + (kt) + (sb >> 1),               \
                 (char*)Vs[buf] + Lb);                                         \
    }                                                                          \
  } while (0)

#define BODY(CUR) do {                                                         \
    f32x4 sacc[2][4];                                                          \
    _Pragma("unroll")                                                          \
    for (int qh = 0; qh < 2; qh++)                                             \
      _Pragma("unroll")                                                        \
      for (int c = 0; c < 4; c++) sacc[qh][c] = zero;                          \
    const char* Kc = (const char*)Ks[CUR];                                     \
    _Pragma("unroll")                                                          \
    for (int c = 0; c < 4; c++) {                                              \
      int row = c * 16 + l15;                                                  \
      int rs = (row & 7) << 4;                                                 \
      const char* kr = Kc + row * 256;                                         \
      _Pragma("unroll")                                                        \
      for (int dc = 0; dc < 4; dc++) {                                         \
        bf16x8 kf = *(const bf16x8*)(kr + ((dc * 64 + lg * 16) ^ rs));         \
        sacc[0][c] = __builtin_amdgcn_mfma_f32_16x16x32_bf16(kf, qf[0][dc], sacc[0][c], 0, 0, 0); \
        sacc[1][c] = __builtin_amdgcn_mfma_f32_16x16x32_bf16(kf, qf[1][dc], sacc[1][c], 0, 0, 0); \
      }                                                                        \
    }                                                                          \
    float px0 = sacc[0][0][0], px1 = sacc[1][0][0];                            \
    _Pragma("unroll")                                                          \
    for (int c = 0; c < 4; c++)                                                \
      _Pragma("unroll")                                                        \
      for (int r = 0; r < 4; r++) {                                            \
        px0 = fmaxf(px0, sacc[0][c][r]);                                       \
        px1 = fmaxf(px1, sacc[1][c][r]);                                       \
      }                                                                        \
    px0 = fmaxf(px0, __shfl_xor(px0, 16)); px0 = fmaxf(px0, __shfl_xor(px0, 32)); \
    px1 = fmaxf(px1, __shfl_xor(px1, 16)); px1 = fmaxf(px1, __shfl_xor(px1, 32)); \
    bool need = (px0 > m0 + 8.f) || (px1 > m1 + 8.f);                          \
    if (__any(need)) {                                                         \
      float mn0 = fmaxf(m0, px0), mn1 = fmaxf(m1, px1);                        \
      float a0 = exp2f(m0 - mn0), a1 = exp2f(m1 - mn1);                        \
      m0 = mn0; m1 = mn1; l0 *= a0; l1 *= a1;                                  \
      _Pragma("unroll")                                                        \
      for (int r = 0; r < 4; r++) {                                            \
        float f0 = __shfl(a0, lg * 4 + r);                                     \
        float f1 = __shfl(a1, lg * 4 + r);                                     \
        _Pragma("unroll")                                                      \
        for (int dn = 0; dn < 8; dn++) { o[0][dn][r] *= f0; o[1][dn][r] *= f1; } \
      }                                                                        \
    }                                                                          \
    _Pragma("unroll")                                                          \
    for (int qh = 0; qh < 2; qh++) {                                           \
      float m = qh ? m1 : m0;                                                  \
      float rsum = 0.f;                                                        \
      char* Prow = (char*)Pw + (qh * 16 + l15) * 128;                          \
      _Pragma("unroll")                                                        \
      for (int c = 0; c < 4; c++) {                                            \
        union { bf16_t b[4]; uint2 u; } pk;                                    \
        _Pragma("unroll")                                                      \
        for (int r = 0; r < 4; r++) {                                          \
          float p = exp2f(sacc[qh][c][r] - m);                                 \
          rsum += p;                                                           \
          pk.b[r] = (bf16_t)p;                                                 \
        }                                                                      \
        *(uint2*)(Prow + ((c * 32 + lg * 8) ^ sw)) = pk.u;                     \
      }                                                                        \
      rsum += __shfl_xor(rsum, 16);                                            \
      rsum += __shfl_xor(rsum, 32);                                            \
      if (qh) l1 += rsum; else l0 += rsum;                                     \
    }                                                                          \
    bf16x8 pf[2][2];                                                           \
    _Pragma("unroll")                                                          \
    for (int qh = 0; qh < 2; qh++) {                                           \
      const char* Prow = (const char*)Pw + (qh * 16 + l15) * 128;              \
      _Pragma("unroll")                                                        \
      for (int kc = 0; kc < 2; kc++)                                           \
        pf[qh][kc] = *(const bf16x8*)(Prow + ((kc * 64 + lg * 16) ^ sw));      \
    }                                                                          \
    const char* Vc = (const char*)Vs[CUR];                                     \
    _Pragma("unroll")                                                          \
    for (int dn = 0; dn < 8; dn++) {                                           \
      int row = dn * 16 + l15;                                                 \
      int rs2 = (row & 7) << 4;                                                \
      const char* vr = Vc + row * 128;                                         \
      bf16x8 vf0 = *(const bf16x8*)(vr + ((lg * 16) ^ rs2));                   \
      bf16x8 vf1 = *(const bf16x8*)(vr + ((64 + lg * 16) ^ rs2));              \
      o[0][dn] = __builtin_amdgcn_mfma_f32_16x16x32_bf16(pf[0][0], vf0, o[0][dn], 0, 0, 0); \
      o[0][dn] = __builtin_amdgcn_mfma_f32_16x16x32_bf16(pf[0][1], vf1, o[0][dn], 0, 0, 0); \
      o[1][dn] = __builtin_amdgcn_mfma_f32_16x16x32_bf16(pf[1][0], vf0, o[1][dn], 0, 0, 0); \
      o[1][dn] = __builtin_amdgcn_mfma_f32_16x16x32_bf16(pf[1][1], vf1, o[1][dn], 0, 0, 0); \
    }                                                                          \
  } while (0)

  STAGE(0, 0);
  __syncthreads();

  const int NT = S_TOT / 64;  // 72 (even)
  for (int tt = 0; tt < NT; tt += 2) {
    STAGE(1, (tt + 1) * 64);
    BODY(0);
    __syncthreads();
    if (tt + 2 < NT) STAGE(0, (tt + 2) * 64);
    BODY(1);
    __syncthreads();
  }
#undef BODY
#undef STAGE

  #pragma unroll
  for (int qh = 0; qh < 2; qh++) {
    #pragma unroll
    for (int r = 0; r < 4; r++) {
      float lv = __shfl(qh ? l1 : l0, lg * 4 + r);
      float inv = 1.f / lv;
      size_t srow = (size_t)q0 + w * 32 + qh * 16 + lg * 4 + r;
      #pragma unroll
      for (int dn = 0; dn < 8; dn++)
        O[srow * DMODEL + h * HD + dn * 16 + l15] = (bf16_t)(o[qh][dn][r] * inv);
    }
  }
}

// ---------------------------------------------------------------------------
extern "C" void kernel_launch(void* const* d_in, const int* in_sizes, int n_in,
                              void* d_out, int out_size, void* d_ws, size_t ws_size,
                              hipStream_t stream) {
  const float* hidden = (const float*)d_in[0];
  const float* enc    = (const float*)d_in[1];
  const float* ropec  = (const float*)d_in[2];
  const float* ropes  = (const float*)d_in[3];
  const float* Wq  = (const float*)d_in[4];
  const float* Wk  = (const float*)d_in[5];
  const float* Wv  = (const float*)d_in[6];
  const float* Waq = (const float*)d_in[7];
  const float* baq = (const float*)d_in[8];
  const float* Wak = (const float*)d_in[9];
  const float* bak = (const float*)d_in[10];
  const float* Wav = (const float*)d_in[11];
  const float* bav = (const float*)d_in[12];
  const float* Wo  = (const float*)d_in[13];
  const float* bo  = (const float*)d_in[14];
  const float* Wao = (const float*)d_in[15];
  const float* bao = (const float*)d_in[16];
  const float* wqn = (const float*)d_in[17];
  const float* wkn = (const float*)d_in[18];
  const float* waqn = (const float*)d_in[19];
  const float* wakn = (const float*)d_in[20];

  const size_t WSZ = (size_t)DMODEL * DMODEL;
  const size_t SEQSZ = (size_t)S_TOT * DMODEL;
  if (ws_size < (2 * WSZ + 6 * SEQSZ) * sizeof(bf16_t)) return;

  bf16_t* s0   = (bf16_t*)d_ws;
  bf16_t* s1   = s0 + WSZ;
  bf16_t* xbi  = s1 + WSZ;
  bf16_t* xbt  = xbi + (size_t)S_IMG * DMODEL;
  bf16_t* qbuf = xbi + SEQSZ;
  bf16_t* kbuf = qbuf + SEQSZ;
  bf16_t* vbuf = kbuf + SEQSZ;   // unused now (V writes Vh directly)
  bf16_t* Kh   = vbuf + SEQSZ;
  bf16_t* Vh   = Kh + SEQSZ;
  bf16_t* Qh   = xbi;      // alias: xb dead after QKV GEMMs
  bf16_t* attn_o = qbuf;   // alias: qbuf dead after qk_post
  float* outf = (float*)d_out;

  f2b_kernel<<<S_IMG * DMODEL / 1024, 256, 0, stream>>>(hidden, xbi, S_IMG * DMODEL);
  f2b_kernel<<<S_TXT * DMODEL / 1024, 256, 0, stream>>>(enc, xbt, S_TXT * DMODEL);

  const int WB = (int)(WSZ / 1024);
  // Q
  f2b2_kernel<<<2 * WB, 256, 0, stream>>>(Wq, s0, Waq, s1, WB);
  gemm1024<bf16_t><<<216, 1024, 0, stream>>>(
      xbi, s0, qbuf + (size_t)S_TXT * DMODEL, nullptr, 16,
      xbt, s1, qbuf, baq, 27);
  // K
  f2b2_kernel<<<2 * WB, 256, 0, stream>>>(Wk, s0, Wak, s1, WB);
  gemm1024<bf16_t><<<216, 1024, 0, stream>>>(
      xbi, s0, kbuf + (size_t)S_TXT * DMODEL, nullptr, 16,
      xbt, s1, kbuf, bak, 27);
  // V: fused transpose epilogue writes Vh[h][d][s] directly
  f2b2_kernel<<<2 * WB, 256, 0, stream>>>(Wv, s0, Wav, s1, WB);
  gemm1024V<<<216, 1024, 0, stream>>>(
      xbi, s0, nullptr, 16, S_TXT,
      xbt, s1, bav, 0, Vh, 27);

  qk_post<<<S_TOT * NH / 4, 256, 0, stream>>>(qbuf, kbuf, ropec, ropes,
                                              wqn, wkn, waqn, wakn, Qh, Kh);

  attn_kernel<<<36 * 24, 256, 0, stream>>>(Qh, Kh, Vh, attn_o);

  f2b2_kernel<<<2 * WB, 256, 0, stream>>>(Wo, s0, Wao, s1, WB);
  gemm1024<float><<<216, 1024, 0, stream>>>(
      attn_o + (size_t)S_TXT * DMODEL, s0, outf, bo, 16,
      attn_o, s1, outf + (size_t)S_IMG * DMODEL, bao, 27);
}